// Round 19
// baseline (194.584 us; speedup 1.0000x reference)
//
#include <hip/hip_runtime.h>
#include <hip/hip_bf16.h>

typedef __attribute__((ext_vector_type(8))) short short8;
typedef __attribute__((ext_vector_type(4))) float floatx4;

#define GLOAD_LDS16(src, dst) \
  __builtin_amdgcn_global_load_lds((const __attribute__((address_space(1))) unsigned int*)(src), \
      (__attribute__((address_space(3))) unsigned int*)(dst), 16, 0, 0)

__device__ __forceinline__ short f2bf(float f) {
    __hip_bfloat16 h = __float2bfloat16(f);
    return *reinterpret_cast<short*>(&h);
}

__device__ __forceinline__ floatx4 mfma16(short8 a, short8 b, floatx4 c) {
    return __builtin_amdgcn_mfma_f32_16x16x32_bf16(a, b, c, 0, 0, 0);
}

// ---------------- Kernel 1: W -> WTf (bf16, 16-col FRAGMENT-MAJOR layout) ----------
// Fragment f = kb*48 + cb (kb 0..31: k = kb*32..+32; cb 0..47: cols cb*16..+16),
// stored as 1 KB at f*1024. Lane l owns 16 B at l*16: 8 bf16 of column
// (cb*16 + (l&15)), k = kb*32 + (l>>4)*8 .. +8 -- the exact 16x16x32 MFMA
// B operand, loadable with ONE coalesced 1KB wave load.
__global__ __launch_bounds__(64) void wconv_kernel(const float* __restrict__ Wq,
                                                   const float* __restrict__ Wk,
                                                   const float* __restrict__ Wv,
                                                   __hip_bfloat16* __restrict__ WTf) {
    const int bid = blockIdx.x;          // 1536 = 32 kb x 48 cb
    const int kb = bid / 48;
    const int cb = bid % 48;
    const int lane = threadIdx.x;
    const int l15 = lane & 15, lg = lane >> 4;
    const int n = cb * 16 + l15;         // 0..767
    const float* W = (n < 256) ? Wq : (n < 512 ? Wk : Wv);
    const int nl = n & 255;
    const int k0 = kb * 32 + lg * 8;

    short8 h;
#pragma unroll
    for (int j = 0; j < 8; ++j)
        h[j] = f2bf(W[(size_t)(k0 + j) * 256 + nl]);
    *(short8*)((char*)WTf + (size_t)bid * 1024 + lane * 16) = h;
}

// ---------------- Kernel 2: projections  q,k,v = x @ W + b ----------------
// BM=32, BN=768 -> 1024 blocks, 6 waves (wave tile 32x128), 16x16x32 MFMA.
// A (x fp32): gload_lds 8 KB/kt (tiny barrier scope), broadcast-read by all waves.
// B: NO LDS -- 1KB coalesced fragment loads from WTf (L2-resident) directly to
//   MFMA operand registers. acc 64 VGPR -> ~3 waves/SIMD, 2 blocks/CU = 12
//   waves/CU of TLP to hide L2 latency (fixes r17's 11%-occupancy failure).
__global__ __launch_bounds__(384) void proj_kernel(const float* __restrict__ x,
                                                   const __hip_bfloat16* __restrict__ WTf,
                                                   const float* __restrict__ bq,
                                                   const float* __restrict__ bk,
                                                   const float* __restrict__ bv,
                                                   __hip_bfloat16* __restrict__ qo,
                                                   __hip_bfloat16* __restrict__ ko,
                                                   __hip_bfloat16* __restrict__ vo) {
    __shared__ __align__(16) float As[32 * 64];               // 8 KB fp32 A-tile
    char* AsB = (char*)As;

    const int tid = threadIdx.x;
    const int m0 = blockIdx.x * 32;         // 1024 blocks; x panels exclusive
    const int wn = tid >> 6;                // wave 0..5: cols wn*128
    const int lane = tid & 63;
    const int l15 = lane & 15, lg = lane >> 4;
    const char* Wf = (const char*)WTf;

    floatx4 acc[2][8];
#pragma unroll
    for (int i = 0; i < 2; ++i)
#pragma unroll
        for (int j = 0; j < 8; ++j) acc[i][j] = (floatx4){0.f, 0.f, 0.f, 0.f};

    for (int kt = 0; kt < 16; ++kt) {
        // ---- stage A (x fp32): 8 KB, 256B rows (32), 16B-granular swizzle
#pragma unroll
        for (int s = 0; s < 2; ++s) {
            int idx = s * 384 + tid;
            if (idx < 512) {                          // wave-uniform split
                int o = idx * 16;
                int row = o >> 8;
                int sb = (o & 255) ^ ((row & 7) << 4);
                const float* src = x + (size_t)(m0 + row) * 1024 + kt * 64 + (sb >> 2);
                GLOAD_LDS16(src, AsB + o);
            }
        }
        __syncthreads();

#pragma unroll
        for (int ks = 0; ks < 2; ++ks) {              // 2 K32-steps per BK=64
            // ---- A fragments: broadcast LDS read + cvt
            short8 af[2];
#pragma unroll
            for (int mt = 0; mt < 2; ++mt) {
                int row = mt * 16 + l15;
                int rb = row * 256, msk = (row & 7) << 4;
                int b0 = ks * 128 + lg * 32;          // fp32 byte offset
                floatx4 f0 = *(const floatx4*)(AsB + rb + (b0 ^ msk));
                floatx4 f1 = *(const floatx4*)(AsB + rb + ((b0 + 16) ^ msk));
                short8 h;
                h[0] = f2bf(f0[0]); h[1] = f2bf(f0[1]); h[2] = f2bf(f0[2]); h[3] = f2bf(f0[3]);
                h[4] = f2bf(f1[0]); h[5] = f2bf(f1[1]); h[6] = f2bf(f1[2]); h[7] = f2bf(f1[3]);
                af[mt] = h;
            }
            // ---- B fragments: coalesced 1KB loads straight from L2
            const size_t fbase = (size_t)((kt * 2 + ks) * 48 + wn * 8);
#pragma unroll
            for (int hh = 0; hh < 2; ++hh) {
                short8 b8[4];
#pragma unroll
                for (int j = 0; j < 4; ++j)
                    b8[j] = *(const short8*)(Wf + ((fbase + hh * 4 + j) << 10) + lane * 16);
#pragma unroll
                for (int j = 0; j < 4; ++j) {
                    int nt = hh * 4 + j;
                    acc[0][nt] = mfma16(af[0], b8[j], acc[0][nt]);
                    acc[1][nt] = mfma16(af[1], b8[j], acc[1][nt]);
                }
            }
        }
        __syncthreads();
    }

    // ---- epilogue: bias (+ log2e/16 scale for q), bf16 store
    // C/D layout (16x16): col = lane&15, row = (lane>>4)*4 + reg
#pragma unroll
    for (int nt = 0; nt < 8; ++nt) {
        int g = wn * 128 + nt * 16 + l15;       // 0..767; mat uniform per (wave,nt)
        int mat = g >> 8;                       // 0=q 1=k 2=v
        const float* bias = (mat == 0) ? bq : (mat == 1 ? bk : bv);
        __hip_bfloat16* ob = (mat == 0) ? qo : (mat == 1 ? ko : vo);
        float scale = (mat == 0) ? 0.09016844005556021f : 1.0f;  // log2(e)/16
        int c = g & 255;
        float bval = bias[c];
#pragma unroll
        for (int mt = 0; mt < 2; ++mt) {
            int row0 = m0 + mt * 16 + lg * 4;
#pragma unroll
            for (int r = 0; r < 4; ++r)
                ob[(size_t)(row0 + r) * 256 + c] = __float2bfloat16((acc[mt][nt][r] + bval) * scale);
        }
    }
}

// ---------------- Kernel 3: causal flash attention (r18 version, kept) ----------------
// QBLK=128 per block (8 waves x 16 q-rows), 256 blocks, LDS 80 KB -> 2 blocks/CU.
__global__ __launch_bounds__(512) void attn_kernel(const __hip_bfloat16* __restrict__ q,
                                                   const __hip_bfloat16* __restrict__ k,
                                                   const __hip_bfloat16* __restrict__ v,
                                                   float* __restrict__ out) {
    __shared__ __align__(16) __hip_bfloat16 Ks[64 * 256];    // 32 KB, swizzled rows of 512B
    __shared__ __align__(16) __hip_bfloat16 VTs[256 * 64];   // 32 KB, V^T, swizzled rows of 128B
    __shared__ __align__(16) __hip_bfloat16 Ps[8][16 * 64];  // 16 KB, per-wave P
    char* KsB = (char*)Ks;
    char* VTB = (char*)VTs;

    const int tid = threadIdx.x;
    const int bid = blockIdx.x;
    const int wgid = (bid & 7) * 32 + (bid >> 3);
    const int qb2 = wgid & 3, b = wgid >> 2;        // q-tile of 128 rows
    const int wid = tid >> 6, lane = tid & 63;
    const int l15 = lane & 15, lg = lane >> 4;
    char* PsB = (char*)(&Ps[wid][0]);

    short8 qf[8];
    const __hip_bfloat16* qrow = q + ((size_t)(b * 512 + qb2 * 128 + wid * 16 + l15)) * 256;
#pragma unroll
    for (int ks = 0; ks < 8; ++ks) qf[ks] = *(const short8*)(qrow + ks * 32 + lg * 8);

    float m_[4], lsum[4];
    floatx4 o[16];
#pragma unroll
    for (int r = 0; r < 4; ++r) { m_[r] = -1e30f; lsum[r] = 0.f; }
#pragma unroll
    for (int dt = 0; dt < 16; ++dt) o[dt] = (floatx4){0.f, 0.f, 0.f, 0.f};

    const int vkv = lane;
    const int vd0 = wid * 8;
    const int nchunks = qb2 * 2 + 2;
    const int qbw = qb2 * 128 + wid * 16;

    for (int c = 0; c < nchunks; ++c) {
        const size_t kvbase = (size_t)(b * 512 + c * 64) * 256;
#pragma unroll
        for (int s = 0; s < 4; ++s) {
            int o_ = s * 8192 + tid * 16;
            int row = o_ >> 9;
            int so = o_ ^ ((row & 7) << 4);
            const __hip_bfloat16* src = k + kvbase + (size_t)row * 256 + ((so & 511) >> 1);
            GLOAD_LDS16(src, KsB + o_);
        }
#pragma unroll
        for (int it = 0; it < 4; ++it) {
            int dbase = vd0 + it * 64;
            short8 vv = *(const short8*)(v + kvbase + (size_t)vkv * 256 + dbase);
#pragma unroll
            for (int j = 0; j < 8; ++j) {
                int d = dbase + j;
                int addr = (d * 128 + vkv * 2) ^ ((d & 7) << 4);
                *(short*)(VTB + addr) = vv[j];
            }
        }
        __syncthreads();

        floatx4 s4[4];
#pragma unroll
        for (int t = 0; t < 4; ++t) s4[t] = (floatx4){0.f, 0.f, 0.f, 0.f};
#pragma unroll
        for (int ks = 0; ks < 8; ++ks) {
#pragma unroll
            for (int t = 0; t < 4; ++t) {
                int kv = t * 16 + l15;
                short8 kf = *(const short8*)(KsB + kv * 512 + ((ks * 64 + lg * 16) ^ ((kv & 7) << 4)));
                s4[t] = mfma16(qf[ks], kf, s4[t]);
            }
        }
        if (c * 64 + 63 > qbw) {
#pragma unroll
            for (int t = 0; t < 4; ++t) {
                int kvg = c * 64 + t * 16 + l15;
#pragma unroll
                for (int r = 0; r < 4; ++r)
                    if (kvg > qbw + lg * 4 + r) s4[t][r] = -1e30f;
            }
        }
        float pm[4], alpha[4], rs[4];
#pragma unroll
        for (int r = 0; r < 4; ++r)
            pm[r] = fmaxf(fmaxf(s4[0][r], s4[1][r]), fmaxf(s4[2][r], s4[3][r]));
#pragma unroll
        for (int off = 1; off <= 8; off <<= 1)
#pragma unroll
            for (int r = 0; r < 4; ++r) pm[r] = fmaxf(pm[r], __shfl_xor(pm[r], off));
#pragma unroll
        for (int r = 0; r < 4; ++r) {
            float mn = fmaxf(m_[r], pm[r]);
            alpha[r] = exp2f(m_[r] - mn);
            m_[r] = mn;
        }
#pragma unroll
        for (int t = 0; t < 4; ++t)
#pragma unroll
            for (int r = 0; r < 4; ++r) s4[t][r] = exp2f(s4[t][r] - m_[r]);
#pragma unroll
        for (int r = 0; r < 4; ++r) rs[r] = s4[0][r] + s4[1][r] + s4[2][r] + s4[3][r];
#pragma unroll
        for (int off = 1; off <= 8; off <<= 1)
#pragma unroll
            for (int r = 0; r < 4; ++r) rs[r] += __shfl_xor(rs[r], off);
#pragma unroll
        for (int r = 0; r < 4; ++r) lsum[r] = lsum[r] * alpha[r] + rs[r];
#pragma unroll
        for (int dt = 0; dt < 16; ++dt) {
            o[dt][0] *= alpha[0]; o[dt][1] *= alpha[1];
            o[dt][2] *= alpha[2]; o[dt][3] *= alpha[3];
        }
#pragma unroll
        for (int t = 0; t < 4; ++t)
#pragma unroll
            for (int r = 0; r < 4; ++r) {
                int qq = lg * 4 + r;
                int addr = (qq * 128 + (t * 16 + l15) * 2) ^ ((qq & 7) << 4);
                *(short*)(PsB + addr) = f2bf(s4[t][r]);
            }
#pragma unroll
        for (int h = 0; h < 2; ++h) {
            short8 pa = *(const short8*)(PsB + l15 * 128 + ((h * 64 + lg * 16) ^ ((l15 & 7) << 4)));
#pragma unroll
            for (int dt = 0; dt < 16; ++dt) {
                int d = dt * 16 + l15;
                short8 vb = *(const short8*)(VTB + d * 128 + ((h * 64 + lg * 16) ^ ((d & 7) << 4)));
                o[dt] = mfma16(pa, vb, o[dt]);
            }
        }
        __syncthreads();
    }

    float inv[4];
#pragma unroll
    for (int r = 0; r < 4; ++r) inv[r] = 1.0f / lsum[r];
    size_t obase = ((size_t)(b * 512 + qb2 * 128 + wid * 16 + lg * 4)) * 256 + l15;
#pragma unroll
    for (int dt = 0; dt < 16; ++dt)
#pragma unroll
        for (int r = 0; r < 4; ++r)
            out[obase + (size_t)r * 256 + dt * 16] = o[dt][r] * inv[r];
}

// ---------------- host launch ----------------
extern "C" void kernel_launch(void* const* d_in, const int* in_sizes, int n_in,
                              void* d_out, int out_size, void* d_ws, size_t ws_size,
                              hipStream_t stream) {
    const float* x  = (const float*)d_in[0];
    const float* Wq = (const float*)d_in[1];
    const float* bq = (const float*)d_in[2];
    const float* Wk = (const float*)d_in[3];
    const float* bk = (const float*)d_in[4];
    const float* Wv = (const float*)d_in[5];
    const float* bv = (const float*)d_in[6];
    float* out = (float*)d_out;

    char* ws = (char*)d_ws;
    __hip_bfloat16* WTf = (__hip_bfloat16*)ws;                      // 1.5 MiB @ 0
    __hip_bfloat16* qo = (__hip_bfloat16*)(ws + (2u << 20));        // 16 MiB each
    __hip_bfloat16* ko = qo + (size_t)32768 * 256;
    __hip_bfloat16* vo = ko + (size_t)32768 * 256;

    wconv_kernel<<<dim3(1536), dim3(64), 0, stream>>>(Wq, Wk, Wv, WTf);
    proj_kernel<<<dim3(1024), dim3(384), 0, stream>>>(x, WTf, bq, bk, bv, qo, ko, vo);
    attn_kernel<<<dim3(256), dim3(512), 0, stream>>>(qo, ko, vo, out);
}

// Round 20
// 130.166 us; speedup vs baseline: 1.4949x; 1.4949x over previous
//
#include <hip/hip_runtime.h>
#include <hip/hip_bf16.h>

typedef __attribute__((ext_vector_type(8))) short short8;
typedef __attribute__((ext_vector_type(4))) float floatx4;
typedef __attribute__((ext_vector_type(16))) float floatx16;

#define GLOAD_LDS16(src, dst) \
  __builtin_amdgcn_global_load_lds((const __attribute__((address_space(1))) unsigned int*)(src), \
      (__attribute__((address_space(3))) unsigned int*)(dst), 16, 0, 0)

__device__ __forceinline__ short f2bf(float f) {
    __hip_bfloat16 h = __float2bfloat16(f);
    return *reinterpret_cast<short*>(&h);
}

__device__ __forceinline__ floatx4 mfma16(short8 a, short8 b, floatx4 c) {
    return __builtin_amdgcn_mfma_f32_16x16x32_bf16(a, b, c, 0, 0, 0);
}

__device__ __forceinline__ floatx16 mfma32(short8 a, short8 b, floatx16 c) {
    return __builtin_amdgcn_mfma_f32_32x32x16_bf16(a, b, c, 0, 0, 0);
}

// ---------------- Kernel 1: W -> WTf (bf16, 32-col FRAGMENT-MAJOR, validated r17/r19) --
// Fragment (kb, cb): cols cb*32..+32, k = kb*16..+16, stored as 1 KB at
// (kb*24+cb)*1024. Lane l (= lh*32+l31) owns 16 B at l*16: 8 bf16 of column
// (cb*32+l31), k = kb*16+lh*8..+8 -- the exact 32x32x16 MFMA B operand.
// kb-major => per-BK32 LDS stage is a PURE LINEAR 48KB copy.
__global__ __launch_bounds__(64) void wconv_kernel(const float* __restrict__ Wq,
                                                   const float* __restrict__ Wk,
                                                   const float* __restrict__ Wv,
                                                   __hip_bfloat16* __restrict__ WTf) {
    const int bid = blockIdx.x;          // 1536 = 64 kb x 24 cb
    const int kb = bid / 24;
    const int cb = bid % 24;
    const int lane = threadIdx.x;
    const int l31 = lane & 31, lh = lane >> 5;
    const int n = cb * 32 + l31;         // 0..767
    const float* W = (n < 256) ? Wq : (n < 512 ? Wk : Wv);
    const int nl = n & 255;
    const int k0 = kb * 16 + lh * 8;

    short8 h;
#pragma unroll
    for (int j = 0; j < 8; ++j)
        h[j] = f2bf(W[(size_t)(k0 + j) * 256 + nl]);
    *(short8*)((char*)WTf + (size_t)bid * 1024 + lane * 16) = h;
}

// ---------------- Kernel 2: projections  q,k,v = x @ W + b ----------------
// BM=128, BN=768, BK=32 -> 256 blocks, LDS = 16KB(A) + 48KB(B frag-major) = 64KB
// -> 2 blocks/CU (cross-block overlap restores the ~10 B/cyc/CU staging rate).
// B ds_reads are fragment-contiguous (1KB per wave) -> conflict-free, no swizzle.
// A mechanics identical to r14. 8 waves (2m x 4n, wave 64x192), 32x32x16 MFMA.
__global__ __launch_bounds__(512) void proj_kernel(const float* __restrict__ x,
                                                   const __hip_bfloat16* __restrict__ WTf,
                                                   const float* __restrict__ bq,
                                                   const float* __restrict__ bk,
                                                   const float* __restrict__ bv,
                                                   __hip_bfloat16* __restrict__ qo,
                                                   __hip_bfloat16* __restrict__ ko,
                                                   __hip_bfloat16* __restrict__ vo) {
    __shared__ __align__(16) char Ab[16384];   // 128 rows x 128B (32 fp32), swizzled
    __shared__ __align__(16) char Bb[49152];   // 48 fragments x 1KB, fragment-major
    const char* WfB = (const char*)WTf;

    const int tid = threadIdx.x;
    const int m0 = blockIdx.x * 128;        // 256 blocks; x panels exclusive
    const int wid = tid >> 6, lane = tid & 63;
    const int wm = wid >> 2, wn = wid & 3;  // wave tile: rows wm*64, cols wn*192
    const int l31 = lane & 31, lh = lane >> 5;

    floatx16 acc[2][6];
#pragma unroll
    for (int i = 0; i < 2; ++i)
#pragma unroll
        for (int j = 0; j < 6; ++j)
#pragma unroll
            for (int e = 0; e < 16; ++e) acc[i][j][e] = 0.f;

    for (int kt = 0; kt < 32; ++kt) {        // BK=32: k = kt*32..+32
        // ---- stage A (x fp32): 16 KB, 128B rows (128), 16B-granular swizzle
#pragma unroll
        for (int s = 0; s < 2; ++s) {
            int o = s * 8192 + tid * 16;
            int row = o >> 7;
            int sb = (o & 127) ^ ((row & 7) << 4);    // inverse swizzle on source
            const float* src = x + (size_t)(m0 + row) * 1024 + kt * 32 + (sb >> 2);
            GLOAD_LDS16(src, Ab + o);
        }
        // ---- stage B: PURE LINEAR 48KB copy from WTf + kt*48KB (fragment-major)
#pragma unroll
        for (int s = 0; s < 6; ++s) {
            int o = s * 8192 + tid * 16;
            GLOAD_LDS16(WfB + (((size_t)kt * 48) << 10) + o, Bb + o);
        }
        __syncthreads();

#pragma unroll
        for (int ks = 0; ks < 2; ++ks) {              // 2 K16-steps per BK=32
            // ---- A fragments: lane row l31, k = ks*16 + lh*8 ..+8
            short8 af[2];
#pragma unroll
            for (int mt = 0; mt < 2; ++mt) {
                int row = wm * 64 + mt * 32 + l31;
                int rb = row * 128, msk = (row & 7) << 4;
                int b0 = ks * 64 + lh * 32;           // fp32 byte offset in 128B row
                floatx4 f0 = *(const floatx4*)(Ab + rb + (b0 ^ msk));
                floatx4 f1 = *(const floatx4*)(Ab + rb + ((b0 + 16) ^ msk));
                short8 h;
                h[0] = f2bf(f0[0]); h[1] = f2bf(f0[1]); h[2] = f2bf(f0[2]); h[3] = f2bf(f0[3]);
                h[4] = f2bf(f1[0]); h[5] = f2bf(f1[1]); h[6] = f2bf(f1[2]); h[7] = f2bf(f1[3]);
                af[mt] = h;
            }
            // ---- B fragments: contiguous 1KB wave reads, conflict-free
#pragma unroll
            for (int nt = 0; nt < 6; ++nt) {
                int f = ks * 24 + wn * 6 + nt;
                short8 b8 = *(const short8*)(Bb + (f << 10) + lane * 16);
                acc[0][nt] = mfma32(af[0], b8, acc[0][nt]);
                acc[1][nt] = mfma32(af[1], b8, acc[1][nt]);
            }
        }
        __syncthreads();
    }

    // ---- epilogue: bias (+ log2e/16 scale for q), bf16 store
    // C/D layout (32x32): col = lane&31, row = (reg&3) + 8*(reg>>2) + 4*(lane>>5)
#pragma unroll
    for (int nt = 0; nt < 6; ++nt) {
        int g = wn * 192 + nt * 32 + l31;       // 0..767; mat uniform per (wave,nt)
        int mat = g >> 8;                       // 0=q 1=k 2=v
        const float* bias = (mat == 0) ? bq : (mat == 1 ? bk : bv);
        __hip_bfloat16* ob = (mat == 0) ? qo : (mat == 1 ? ko : vo);
        float scale = (mat == 0) ? 0.09016844005556021f : 1.0f;  // log2(e)/16
        int c = g & 255;
        float bval = bias[c];
#pragma unroll
        for (int mt = 0; mt < 2; ++mt) {
            int base_row = m0 + wm * 64 + mt * 32 + lh * 4;
#pragma unroll
            for (int reg = 0; reg < 16; ++reg) {
                int row = base_row + (reg & 3) + 8 * (reg >> 2);
                ob[(size_t)row * 256 + c] = __float2bfloat16((acc[mt][nt][reg] + bval) * scale);
            }
        }
    }
}

// ---------------- Kernel 3: causal flash attention (r18 version, best) ----------------
// QBLK=128 per block (8 waves x 16 q-rows), 256 blocks, LDS 80 KB -> 2 blocks/CU.
__global__ __launch_bounds__(512) void attn_kernel(const __hip_bfloat16* __restrict__ q,
                                                   const __hip_bfloat16* __restrict__ k,
                                                   const __hip_bfloat16* __restrict__ v,
                                                   float* __restrict__ out) {
    __shared__ __align__(16) __hip_bfloat16 Ks[64 * 256];    // 32 KB, swizzled rows of 512B
    __shared__ __align__(16) __hip_bfloat16 VTs[256 * 64];   // 32 KB, V^T, swizzled rows of 128B
    __shared__ __align__(16) __hip_bfloat16 Ps[8][16 * 64];  // 16 KB, per-wave P
    char* KsB = (char*)Ks;
    char* VTB = (char*)VTs;

    const int tid = threadIdx.x;
    const int bid = blockIdx.x;
    const int wgid = (bid & 7) * 32 + (bid >> 3);
    const int qb2 = wgid & 3, b = wgid >> 2;        // q-tile of 128 rows
    const int wid = tid >> 6, lane = tid & 63;
    const int l15 = lane & 15, lg = lane >> 4;
    char* PsB = (char*)(&Ps[wid][0]);

    short8 qf[8];
    const __hip_bfloat16* qrow = q + ((size_t)(b * 512 + qb2 * 128 + wid * 16 + l15)) * 256;
#pragma unroll
    for (int ks = 0; ks < 8; ++ks) qf[ks] = *(const short8*)(qrow + ks * 32 + lg * 8);

    float m_[4], lsum[4];
    floatx4 o[16];
#pragma unroll
    for (int r = 0; r < 4; ++r) { m_[r] = -1e30f; lsum[r] = 0.f; }
#pragma unroll
    for (int dt = 0; dt < 16; ++dt) o[dt] = (floatx4){0.f, 0.f, 0.f, 0.f};

    const int vkv = lane;
    const int vd0 = wid * 8;
    const int nchunks = qb2 * 2 + 2;
    const int qbw = qb2 * 128 + wid * 16;

    for (int c = 0; c < nchunks; ++c) {
        const size_t kvbase = (size_t)(b * 512 + c * 64) * 256;
#pragma unroll
        for (int s = 0; s < 4; ++s) {
            int o_ = s * 8192 + tid * 16;
            int row = o_ >> 9;
            int so = o_ ^ ((row & 7) << 4);
            const __hip_bfloat16* src = k + kvbase + (size_t)row * 256 + ((so & 511) >> 1);
            GLOAD_LDS16(src, KsB + o_);
        }
#pragma unroll
        for (int it = 0; it < 4; ++it) {
            int dbase = vd0 + it * 64;
            short8 vv = *(const short8*)(v + kvbase + (size_t)vkv * 256 + dbase);
#pragma unroll
            for (int j = 0; j < 8; ++j) {
                int d = dbase + j;
                int addr = (d * 128 + vkv * 2) ^ ((d & 7) << 4);
                *(short*)(VTB + addr) = vv[j];
            }
        }
        __syncthreads();

        floatx4 s4[4];
#pragma unroll
        for (int t = 0; t < 4; ++t) s4[t] = (floatx4){0.f, 0.f, 0.f, 0.f};
#pragma unroll
        for (int ks = 0; ks < 8; ++ks) {
#pragma unroll
            for (int t = 0; t < 4; ++t) {
                int kv = t * 16 + l15;
                short8 kf = *(const short8*)(KsB + kv * 512 + ((ks * 64 + lg * 16) ^ ((kv & 7) << 4)));
                s4[t] = mfma16(qf[ks], kf, s4[t]);
            }
        }
        if (c * 64 + 63 > qbw) {
#pragma unroll
            for (int t = 0; t < 4; ++t) {
                int kvg = c * 64 + t * 16 + l15;
#pragma unroll
                for (int r = 0; r < 4; ++r)
                    if (kvg > qbw + lg * 4 + r) s4[t][r] = -1e30f;
            }
        }
        float pm[4], alpha[4], rs[4];
#pragma unroll
        for (int r = 0; r < 4; ++r)
            pm[r] = fmaxf(fmaxf(s4[0][r], s4[1][r]), fmaxf(s4[2][r], s4[3][r]));
#pragma unroll
        for (int off = 1; off <= 8; off <<= 1)
#pragma unroll
            for (int r = 0; r < 4; ++r) pm[r] = fmaxf(pm[r], __shfl_xor(pm[r], off));
#pragma unroll
        for (int r = 0; r < 4; ++r) {
            float mn = fmaxf(m_[r], pm[r]);
            alpha[r] = exp2f(m_[r] - mn);
            m_[r] = mn;
        }
#pragma unroll
        for (int t = 0; t < 4; ++t)
#pragma unroll
            for (int r = 0; r < 4; ++r) s4[t][r] = exp2f(s4[t][r] - m_[r]);
#pragma unroll
        for (int r = 0; r < 4; ++r) rs[r] = s4[0][r] + s4[1][r] + s4[2][r] + s4[3][r];
#pragma unroll
        for (int off = 1; off <= 8; off <<= 1)
#pragma unroll
            for (int r = 0; r < 4; ++r) rs[r] += __shfl_xor(rs[r], off);
#pragma unroll
        for (int r = 0; r < 4; ++r) lsum[r] = lsum[r] * alpha[r] + rs[r];
#pragma unroll
        for (int dt = 0; dt < 16; ++dt) {
            o[dt][0] *= alpha[0]; o[dt][1] *= alpha[1];
            o[dt][2] *= alpha[2]; o[dt][3] *= alpha[3];
        }
#pragma unroll
        for (int t = 0; t < 4; ++t)
#pragma unroll
            for (int r = 0; r < 4; ++r) {
                int qq = lg * 4 + r;
                int addr = (qq * 128 + (t * 16 + l15) * 2) ^ ((qq & 7) << 4);
                *(short*)(PsB + addr) = f2bf(s4[t][r]);
            }
#pragma unroll
        for (int h = 0; h < 2; ++h) {
            short8 pa = *(const short8*)(PsB + l15 * 128 + ((h * 64 + lg * 16) ^ ((l15 & 7) << 4)));
#pragma unroll
            for (int dt = 0; dt < 16; ++dt) {
                int d = dt * 16 + l15;
                short8 vb = *(const short8*)(VTB + d * 128 + ((h * 64 + lg * 16) ^ ((d & 7) << 4)));
                o[dt] = mfma16(pa, vb, o[dt]);
            }
        }
        __syncthreads();
    }

    float inv[4];
#pragma unroll
    for (int r = 0; r < 4; ++r) inv[r] = 1.0f / lsum[r];
    size_t obase = ((size_t)(b * 512 + qb2 * 128 + wid * 16 + lg * 4)) * 256 + l15;
#pragma unroll
    for (int dt = 0; dt < 16; ++dt)
#pragma unroll
        for (int r = 0; r < 4; ++r)
            out[obase + (size_t)r * 256 + dt * 16] = o[dt][r] * inv[r];
}

// ---------------- host launch ----------------
extern "C" void kernel_launch(void* const* d_in, const int* in_sizes, int n_in,
                              void* d_out, int out_size, void* d_ws, size_t ws_size,
                              hipStream_t stream) {
    const float* x  = (const float*)d_in[0];
    const float* Wq = (const float*)d_in[1];
    const float* bq = (const float*)d_in[2];
    const float* Wk = (const float*)d_in[3];
    const float* bk = (const float*)d_in[4];
    const float* Wv = (const float*)d_in[5];
    const float* bv = (const float*)d_in[6];
    float* out = (float*)d_out;

    char* ws = (char*)d_ws;
    __hip_bfloat16* WTf = (__hip_bfloat16*)ws;                      // 1.5 MiB @ 0
    __hip_bfloat16* qo = (__hip_bfloat16*)(ws + (2u << 20));        // 16 MiB each
    __hip_bfloat16* ko = qo + (size_t)32768 * 256;
    __hip_bfloat16* vo = ko + (size_t)32768 * 256;

    wconv_kernel<<<dim3(1536), dim3(64), 0, stream>>>(Wq, Wk, Wv, WTf);
    proj_kernel<<<dim3(256), dim3(512), 0, stream>>>(x, WTf, bq, bk, bv, qo, ko, vo);
    attn_kernel<<<dim3(256), dim3(512), 0, stream>>>(qo, ko, vo, out);
}

// Round 21
// 129.401 us; speedup vs baseline: 1.5037x; 1.0059x over previous
//
#include <hip/hip_runtime.h>
#include <hip/hip_bf16.h>

typedef __attribute__((ext_vector_type(8))) short short8;
typedef __attribute__((ext_vector_type(4))) float floatx4;
typedef __attribute__((ext_vector_type(16))) float floatx16;

#define GLOAD_LDS16(src, dst) \
  __builtin_amdgcn_global_load_lds((const __attribute__((address_space(1))) unsigned int*)(src), \
      (__attribute__((address_space(3))) unsigned int*)(dst), 16, 0, 0)

__device__ __forceinline__ short f2bf(float f) {
    __hip_bfloat16 h = __float2bfloat16(f);
    return *reinterpret_cast<short*>(&h);
}

__device__ __forceinline__ floatx4 mfma16(short8 a, short8 b, floatx4 c) {
    return __builtin_amdgcn_mfma_f32_16x16x32_bf16(a, b, c, 0, 0, 0);
}

__device__ __forceinline__ floatx16 mfma32(short8 a, short8 b, floatx16 c) {
    return __builtin_amdgcn_mfma_f32_32x32x16_bf16(a, b, c, 0, 0, 0);
}

// ---------------- Kernel 1: W -> WTf (bf16, 32-col FRAGMENT-MAJOR, validated) --------
// Fragment (kb, cb): cols cb*32..+32, k = kb*16..+16, 1 KB at (kb*24+cb)*1024.
// Lane l (= lh*32+l31) owns 16 B at l*16: 8 bf16 of column (cb*32+l31),
// k = kb*16+lh*8..+8 -- the exact 32x32x16 MFMA B operand. kb-major =>
// a BK=64 stage is TWO linear 48KB copies (one contiguous 96KB slice per kt).
__global__ __launch_bounds__(64) void wconv_kernel(const float* __restrict__ Wq,
                                                   const float* __restrict__ Wk,
                                                   const float* __restrict__ Wv,
                                                   __hip_bfloat16* __restrict__ WTf) {
    const int bid = blockIdx.x;          // 1536 = 64 kb x 24 cb
    const int kb = bid / 24;
    const int cb = bid % 24;
    const int lane = threadIdx.x;
    const int l31 = lane & 31, lh = lane >> 5;
    const int n = cb * 32 + l31;         // 0..767
    const float* W = (n < 256) ? Wq : (n < 512 ? Wk : Wv);
    const int nl = n & 255;
    const int k0 = kb * 16 + lh * 8;

    short8 h;
#pragma unroll
    for (int j = 0; j < 8; ++j)
        h[j] = f2bf(W[(size_t)(k0 + j) * 256 + nl]);
    *(short8*)((char*)WTf + (size_t)bid * 1024 + lane * 16) = h;
}

// ---------------- Kernel 2: projections  q,k,v = x @ W + b ----------------
// r14 structure (best proj: BN=768, BM=128, BK=64, 256 blocks, 32 barriers,
// 32x32x16 MFMA, x staged once) + r20's fragment-major B (linear 96KB stage,
// conflict-free contiguous 1KB wave reads, no B swizzle ALU).
__global__ __launch_bounds__(512) void proj_kernel(const float* __restrict__ x,
                                                   const __hip_bfloat16* __restrict__ WTf,
                                                   const float* __restrict__ bq,
                                                   const float* __restrict__ bk,
                                                   const float* __restrict__ bv,
                                                   __hip_bfloat16* __restrict__ qo,
                                                   __hip_bfloat16* __restrict__ ko,
                                                   __hip_bfloat16* __restrict__ vo) {
    __shared__ __align__(16) char Ab[32768];   // 128 rows x 256B (64 fp32), swizzled
    __shared__ __align__(16) char Bb[98304];   // 96 fragments x 1KB, fragment-major
    const char* WfB = (const char*)WTf;

    const int tid = threadIdx.x;
    const int m0 = blockIdx.x * 128;        // 256 blocks; x panels exclusive
    const int wid = tid >> 6, lane = tid & 63;
    const int wm = wid >> 2, wn = wid & 3;  // wave tile: rows wm*64, cols wn*192
    const int l31 = lane & 31, lh = lane >> 5;

    floatx16 acc[2][6];
#pragma unroll
    for (int i = 0; i < 2; ++i)
#pragma unroll
        for (int j = 0; j < 6; ++j)
#pragma unroll
            for (int e = 0; e < 16; ++e) acc[i][j][e] = 0.f;

    for (int kt = 0; kt < 16; ++kt) {        // BK=64: k = kt*64..+64
        // ---- stage A (x fp32): 32 KB, 256B rows (128), 16B-granular swizzle (r14)
#pragma unroll
        for (int s = 0; s < 4; ++s) {
            int o = s * 8192 + tid * 16;
            int row = o >> 8;
            int sb = (o & 255) ^ ((row & 7) << 4);    // inverse swizzle on source
            const float* src = x + (size_t)(m0 + row) * 1024 + kt * 64 + (sb >> 2);
            GLOAD_LDS16(src, Ab + o);
        }
        // ---- stage B: PURE LINEAR 96KB copy from WTf + kt*96KB (fragment-major)
#pragma unroll
        for (int s = 0; s < 12; ++s) {
            int o = s * 8192 + tid * 16;
            GLOAD_LDS16(WfB + (((size_t)kt * 96) << 10) + o, Bb + o);
        }
        __syncthreads();

#pragma unroll
        for (int ks = 0; ks < 4; ++ks) {              // 4 K16-steps per BK=64
            // ---- A fragments: lane row l31, k = ks*16 + lh*8 ..+8
            short8 af[2];
#pragma unroll
            for (int mt = 0; mt < 2; ++mt) {
                int row = wm * 64 + mt * 32 + l31;
                int rb = row * 256, msk = (row & 7) << 4;
                int b0 = ks * 64 + lh * 32;           // fp32 byte offset in 256B row
                floatx4 f0 = *(const floatx4*)(Ab + rb + (b0 ^ msk));
                floatx4 f1 = *(const floatx4*)(Ab + rb + ((b0 + 16) ^ msk));
                short8 h;
                h[0] = f2bf(f0[0]); h[1] = f2bf(f0[1]); h[2] = f2bf(f0[2]); h[3] = f2bf(f0[3]);
                h[4] = f2bf(f1[0]); h[5] = f2bf(f1[1]); h[6] = f2bf(f1[2]); h[7] = f2bf(f1[3]);
                af[mt] = h;
            }
            // ---- B fragments: contiguous 1KB wave reads, conflict-free
#pragma unroll
            for (int nt = 0; nt < 6; ++nt) {
                int f = ks * 24 + wn * 6 + nt;
                short8 b8 = *(const short8*)(Bb + (f << 10) + lane * 16);
                acc[0][nt] = mfma32(af[0], b8, acc[0][nt]);
                acc[1][nt] = mfma32(af[1], b8, acc[1][nt]);
            }
        }
        __syncthreads();
    }

    // ---- epilogue: bias (+ log2e/16 scale for q), bf16 store
    // C/D layout (32x32): col = lane&31, row = (reg&3) + 8*(reg>>2) + 4*(lane>>5)
#pragma unroll
    for (int nt = 0; nt < 6; ++nt) {
        int g = wn * 192 + nt * 32 + l31;       // 0..767; mat uniform per (wave,nt)
        int mat = g >> 8;                       // 0=q 1=k 2=v
        const float* bias = (mat == 0) ? bq : (mat == 1 ? bk : bv);
        __hip_bfloat16* ob = (mat == 0) ? qo : (mat == 1 ? ko : vo);
        float scale = (mat == 0) ? 0.09016844005556021f : 1.0f;  // log2(e)/16
        int c = g & 255;
        float bval = bias[c];
#pragma unroll
        for (int mt = 0; mt < 2; ++mt) {
            int base_row = m0 + wm * 64 + mt * 32 + lh * 4;
#pragma unroll
            for (int reg = 0; reg < 16; ++reg) {
                int row = base_row + (reg & 3) + 8 * (reg >> 2);
                ob[(size_t)row * 256 + c] = __float2bfloat16((acc[mt][nt][reg] + bval) * scale);
            }
        }
    }
}

// ---------------- Kernel 3: causal flash attention (r18 version, best) ----------------
// QBLK=128 per block (8 waves x 16 q-rows), 256 blocks, LDS 80 KB -> 2 blocks/CU.
__global__ __launch_bounds__(512) void attn_kernel(const __hip_bfloat16* __restrict__ q,
                                                   const __hip_bfloat16* __restrict__ k,
                                                   const __hip_bfloat16* __restrict__ v,
                                                   float* __restrict__ out) {
    __shared__ __align__(16) __hip_bfloat16 Ks[64 * 256];    // 32 KB, swizzled rows of 512B
    __shared__ __align__(16) __hip_bfloat16 VTs[256 * 64];   // 32 KB, V^T, swizzled rows of 128B
    __shared__ __align__(16) __hip_bfloat16 Ps[8][16 * 64];  // 16 KB, per-wave P
    char* KsB = (char*)Ks;
    char* VTB = (char*)VTs;

    const int tid = threadIdx.x;
    const int bid = blockIdx.x;
    const int wgid = (bid & 7) * 32 + (bid >> 3);
    const int qb2 = wgid & 3, b = wgid >> 2;        // q-tile of 128 rows
    const int wid = tid >> 6, lane = tid & 63;
    const int l15 = lane & 15, lg = lane >> 4;
    char* PsB = (char*)(&Ps[wid][0]);

    short8 qf[8];
    const __hip_bfloat16* qrow = q + ((size_t)(b * 512 + qb2 * 128 + wid * 16 + l15)) * 256;
#pragma unroll
    for (int ks = 0; ks < 8; ++ks) qf[ks] = *(const short8*)(qrow + ks * 32 + lg * 8);

    float m_[4], lsum[4];
    floatx4 o[16];
#pragma unroll
    for (int r = 0; r < 4; ++r) { m_[r] = -1e30f; lsum[r] = 0.f; }
#pragma unroll
    for (int dt = 0; dt < 16; ++dt) o[dt] = (floatx4){0.f, 0.f, 0.f, 0.f};

    const int vkv = lane;
    const int vd0 = wid * 8;
    const int nchunks = qb2 * 2 + 2;
    const int qbw = qb2 * 128 + wid * 16;

    for (int c = 0; c < nchunks; ++c) {
        const size_t kvbase = (size_t)(b * 512 + c * 64) * 256;
#pragma unroll
        for (int s = 0; s < 4; ++s) {
            int o_ = s * 8192 + tid * 16;
            int row = o_ >> 9;
            int so = o_ ^ ((row & 7) << 4);
            const __hip_bfloat16* src = k + kvbase + (size_t)row * 256 + ((so & 511) >> 1);
            GLOAD_LDS16(src, KsB + o_);
        }
#pragma unroll
        for (int it = 0; it < 4; ++it) {
            int dbase = vd0 + it * 64;
            short8 vv = *(const short8*)(v + kvbase + (size_t)vkv * 256 + dbase);
#pragma unroll
            for (int j = 0; j < 8; ++j) {
                int d = dbase + j;
                int addr = (d * 128 + vkv * 2) ^ ((d & 7) << 4);
                *(short*)(VTB + addr) = vv[j];
            }
        }
        __syncthreads();

        floatx4 s4[4];
#pragma unroll
        for (int t = 0; t < 4; ++t) s4[t] = (floatx4){0.f, 0.f, 0.f, 0.f};
#pragma unroll
        for (int ks = 0; ks < 8; ++ks) {
#pragma unroll
            for (int t = 0; t < 4; ++t) {
                int kv = t * 16 + l15;
                short8 kf = *(const short8*)(KsB + kv * 512 + ((ks * 64 + lg * 16) ^ ((kv & 7) << 4)));
                s4[t] = mfma16(qf[ks], kf, s4[t]);
            }
        }
        if (c * 64 + 63 > qbw) {
#pragma unroll
            for (int t = 0; t < 4; ++t) {
                int kvg = c * 64 + t * 16 + l15;
#pragma unroll
                for (int r = 0; r < 4; ++r)
                    if (kvg > qbw + lg * 4 + r) s4[t][r] = -1e30f;
            }
        }
        float pm[4], alpha[4], rs[4];
#pragma unroll
        for (int r = 0; r < 4; ++r)
            pm[r] = fmaxf(fmaxf(s4[0][r], s4[1][r]), fmaxf(s4[2][r], s4[3][r]));
#pragma unroll
        for (int off = 1; off <= 8; off <<= 1)
#pragma unroll
            for (int r = 0; r < 4; ++r) pm[r] = fmaxf(pm[r], __shfl_xor(pm[r], off));
#pragma unroll
        for (int r = 0; r < 4; ++r) {
            float mn = fmaxf(m_[r], pm[r]);
            alpha[r] = exp2f(m_[r] - mn);
            m_[r] = mn;
        }
#pragma unroll
        for (int t = 0; t < 4; ++t)
#pragma unroll
            for (int r = 0; r < 4; ++r) s4[t][r] = exp2f(s4[t][r] - m_[r]);
#pragma unroll
        for (int r = 0; r < 4; ++r) rs[r] = s4[0][r] + s4[1][r] + s4[2][r] + s4[3][r];
#pragma unroll
        for (int off = 1; off <= 8; off <<= 1)
#pragma unroll
            for (int r = 0; r < 4; ++r) rs[r] += __shfl_xor(rs[r], off);
#pragma unroll
        for (int r = 0; r < 4; ++r) lsum[r] = lsum[r] * alpha[r] + rs[r];
#pragma unroll
        for (int dt = 0; dt < 16; ++dt) {
            o[dt][0] *= alpha[0]; o[dt][1] *= alpha[1];
            o[dt][2] *= alpha[2]; o[dt][3] *= alpha[3];
        }
#pragma unroll
        for (int t = 0; t < 4; ++t)
#pragma unroll
            for (int r = 0; r < 4; ++r) {
                int qq = lg * 4 + r;
                int addr = (qq * 128 + (t * 16 + l15) * 2) ^ ((qq & 7) << 4);
                *(short*)(PsB + addr) = f2bf(s4[t][r]);
            }
#pragma unroll
        for (int h = 0; h < 2; ++h) {
            short8 pa = *(const short8*)(PsB + l15 * 128 + ((h * 64 + lg * 16) ^ ((l15 & 7) << 4)));
#pragma unroll
            for (int dt = 0; dt < 16; ++dt) {
                int d = dt * 16 + l15;
                short8 vb = *(const short8*)(VTB + d * 128 + ((h * 64 + lg * 16) ^ ((d & 7) << 4)));
                o[dt] = mfma16(pa, vb, o[dt]);
            }
        }
        __syncthreads();
    }

    float inv[4];
#pragma unroll
    for (int r = 0; r < 4; ++r) inv[r] = 1.0f / lsum[r];
    size_t obase = ((size_t)(b * 512 + qb2 * 128 + wid * 16 + lg * 4)) * 256 + l15;
#pragma unroll
    for (int dt = 0; dt < 16; ++dt)
#pragma unroll
        for (int r = 0; r < 4; ++r)
            out[obase + (size_t)r * 256 + dt * 16] = o[dt][r] * inv[r];
}

// ---------------- host launch ----------------
extern "C" void kernel_launch(void* const* d_in, const int* in_sizes, int n_in,
                              void* d_out, int out_size, void* d_ws, size_t ws_size,
                              hipStream_t stream) {
    const float* x  = (const float*)d_in[0];
    const float* Wq = (const float*)d_in[1];
    const float* bq = (const float*)d_in[2];
    const float* Wk = (const float*)d_in[3];
    const float* bk = (const float*)d_in[4];
    const float* Wv = (const float*)d_in[5];
    const float* bv = (const float*)d_in[6];
    float* out = (float*)d_out;

    char* ws = (char*)d_ws;
    __hip_bfloat16* WTf = (__hip_bfloat16*)ws;                      // 1.5 MiB @ 0
    __hip_bfloat16* qo = (__hip_bfloat16*)(ws + (2u << 20));        // 16 MiB each
    __hip_bfloat16* ko = qo + (size_t)32768 * 256;
    __hip_bfloat16* vo = ko + (size_t)32768 * 256;

    wconv_kernel<<<dim3(1536), dim3(64), 0, stream>>>(Wq, Wk, Wv, WTf);
    proj_kernel<<<dim3(256), dim3(512), 0, stream>>>(x, WTf, bq, bk, bv, qo, ko, vo);
    attn_kernel<<<dim3(256), dim3(512), 0, stream>>>(qo, ko, vo, out);
}

// Round 22
// 129.276 us; speedup vs baseline: 1.5052x; 1.0010x over previous
//
#include <hip/hip_runtime.h>
#include <hip/hip_bf16.h>

typedef __attribute__((ext_vector_type(8))) short short8;
typedef __attribute__((ext_vector_type(4))) float floatx4;
typedef __attribute__((ext_vector_type(16))) float floatx16;

#define GLOAD_LDS16(src, dst) \
  __builtin_amdgcn_global_load_lds((const __attribute__((address_space(1))) unsigned int*)(src), \
      (__attribute__((address_space(3))) unsigned int*)(dst), 16, 0, 0)

__device__ __forceinline__ short f2bf(float f) {
    __hip_bfloat16 h = __float2bfloat16(f);
    return *reinterpret_cast<short*>(&h);
}

__device__ __forceinline__ floatx4 mfma16(short8 a, short8 b, floatx4 c) {
    return __builtin_amdgcn_mfma_f32_16x16x32_bf16(a, b, c, 0, 0, 0);
}

__device__ __forceinline__ floatx16 mfma32(short8 a, short8 b, floatx16 c) {
    return __builtin_amdgcn_mfma_f32_32x32x16_bf16(a, b, c, 0, 0, 0);
}

// ---------------- Kernel 1: W -> WT via LDS-tiled transpose (coalesced both sides) ----
__global__ __launch_bounds__(256) void wconv_kernel(const float* __restrict__ Wq,
                                                    const float* __restrict__ Wk,
                                                    const float* __restrict__ Wv,
                                                    __hip_bfloat16* __restrict__ WT) {
    __shared__ unsigned short lds[64][65];          // +1 pad: conflict-free transpose
    const int bidx = blockIdx.x;
    const int kt = bidx & 15;                       // k-tile (k0 = kt*64)
    const int ntile = bidx >> 4;                    // 0..11 (global n0 = ntile*64)
    const int gn0 = ntile * 64;
    const float* W = (gn0 < 256) ? Wq : (gn0 < 512 ? Wk : Wv);
    const int nl0 = gn0 & 255;
    const int k0 = kt * 64;
    const int tr = threadIdx.x >> 6;                // 0..3
    const int tc = threadIdx.x & 63;

#pragma unroll
    for (int it = 0; it < 16; ++it) {
        int r = it * 4 + tr;                        // k-row in tile
        lds[r][tc] = (unsigned short)f2bf(W[(size_t)(k0 + r) * 256 + nl0 + tc]);
    }
    __syncthreads();
#pragma unroll
    for (int it = 0; it < 16; ++it) {
        int nr = it * 4 + tr;                       // n-row in tile
        unsigned short u = lds[tc][nr];
        WT[(size_t)(gn0 + nr) * 1024 + k0 + tc] = *reinterpret_cast<__hip_bfloat16*>(&u);
    }
}

// ---------------- Kernel 2: projections  q,k,v = x @ W + b (r14 version, best) ----
// BN=768 (all outputs per block), BM=128, BK=64 -> 256 blocks, 1 per CU.
// x staged EXACTLY ONCE; B = full WT slice per kt (L2-resident). 32x32x16 MFMA.
__global__ __launch_bounds__(512) void proj_kernel(const float* __restrict__ x,
                                                   const __hip_bfloat16* __restrict__ WT,
                                                   const float* __restrict__ bq,
                                                   const float* __restrict__ bk,
                                                   const float* __restrict__ bv,
                                                   __hip_bfloat16* __restrict__ qo,
                                                   __hip_bfloat16* __restrict__ ko,
                                                   __hip_bfloat16* __restrict__ vo) {
    __shared__ __align__(16) float As[128 * 64];              // 32 KB fp32 A-tile
    __shared__ __align__(16) __hip_bfloat16 Bs[768 * 64];     // 96 KB bf16 B-tile
    char* AsB = (char*)As;
    char* BsB = (char*)Bs;

    const int tid = threadIdx.x;
    const int m0 = blockIdx.x * 128;        // 256 blocks; x panels are exclusive
    const int wid = tid >> 6, lane = tid & 63;
    const int wm = wid >> 2, wn = wid & 3;  // wave tile: rows wm*64, cols wn*192
    const int l31 = lane & 31, lh = lane >> 5;

    floatx16 acc[2][6];                     // 192 acc VGPR
#pragma unroll
    for (int i = 0; i < 2; ++i)
#pragma unroll
        for (int j = 0; j < 6; ++j)
#pragma unroll
            for (int e = 0; e < 16; ++e) acc[i][j][e] = 0.f;

    for (int kt = 0; kt < 16; ++kt) {
#pragma unroll
        for (int s = 0; s < 4; ++s) {
            int o = s * 8192 + tid * 16;
            int row = o >> 8;
            int sb = (o & 255) ^ ((row & 7) << 4);    // inverse swizzle on source
            const float* src = x + (size_t)(m0 + row) * 1024 + kt * 64 + (sb >> 2);
            GLOAD_LDS16(src, AsB + o);
        }
#pragma unroll
        for (int s = 0; s < 12; ++s) {
            int o = s * 8192 + tid * 16;
            int row = o >> 7;
            int so = (o & 127) ^ ((row & 7) << 4);
            const __hip_bfloat16* src = WT + (size_t)row * 1024 + kt * 64 + (so >> 1);
            GLOAD_LDS16(src, BsB + o);
        }
        __syncthreads();

#pragma unroll
        for (int ks = 0; ks < 4; ++ks) {              // 4 K16-steps per BK=64
            short8 af[2];
#pragma unroll
            for (int mt = 0; mt < 2; ++mt) {
                int row = wm * 64 + mt * 32 + l31;
                int rb = row * 256, msk = (row & 7) << 4;
                int b0 = ks * 64 + lh * 32;           // fp32 byte offset
                floatx4 f0 = *(const floatx4*)(AsB + rb + (b0 ^ msk));
                floatx4 f1 = *(const floatx4*)(AsB + rb + ((b0 + 16) ^ msk));
                short8 h;
                h[0] = f2bf(f0[0]); h[1] = f2bf(f0[1]); h[2] = f2bf(f0[2]); h[3] = f2bf(f0[3]);
                h[4] = f2bf(f1[0]); h[5] = f2bf(f1[1]); h[6] = f2bf(f1[2]); h[7] = f2bf(f1[3]);
                af[mt] = h;
            }
#pragma unroll
            for (int nt = 0; nt < 6; ++nt) {
                int row = wn * 192 + nt * 32 + l31;
                int off = ks * 32 + lh * 16;          // bf16 byte offset in 128B row
                short8 b8 = *(const short8*)(BsB + row * 128 + (off ^ ((row & 7) << 4)));
                acc[0][nt] = mfma32(af[0], b8, acc[0][nt]);
                acc[1][nt] = mfma32(af[1], b8, acc[1][nt]);
            }
        }
        __syncthreads();
    }

    // C/D layout (32x32): col = lane&31, row = (reg&3) + 8*(reg>>2) + 4*(lane>>5)
#pragma unroll
    for (int nt = 0; nt < 6; ++nt) {
        int g = wn * 192 + nt * 32 + l31;       // 0..767; mat uniform per (wave,nt)
        int mat = g >> 8;                       // 0=q 1=k 2=v
        const float* bias = (mat == 0) ? bq : (mat == 1 ? bk : bv);
        __hip_bfloat16* ob = (mat == 0) ? qo : (mat == 1 ? ko : vo);
        float scale = (mat == 0) ? 0.09016844005556021f : 1.0f;  // log2(e)/16
        int c = g & 255;
        float bval = bias[c];
#pragma unroll
        for (int mt = 0; mt < 2; ++mt) {
            int base_row = m0 + wm * 64 + mt * 32 + lh * 4;
#pragma unroll
            for (int reg = 0; reg < 16; ++reg) {
                int row = base_row + (reg & 3) + 8 * (reg >> 2);
                ob[(size_t)row * 256 + c] = __float2bfloat16((acc[mt][nt][reg] + bval) * scale);
            }
        }
    }
}

// ---------------- Kernel 3: causal flash attention (r18 version, best) ----------------
// QBLK=128 per block (8 waves x 16 q-rows), 256 blocks, LDS 80 KB -> 2 blocks/CU.
__global__ __launch_bounds__(512) void attn_kernel(const __hip_bfloat16* __restrict__ q,
                                                   const __hip_bfloat16* __restrict__ k,
                                                   const __hip_bfloat16* __restrict__ v,
                                                   float* __restrict__ out) {
    __shared__ __align__(16) __hip_bfloat16 Ks[64 * 256];    // 32 KB, swizzled rows of 512B
    __shared__ __align__(16) __hip_bfloat16 VTs[256 * 64];   // 32 KB, V^T, swizzled rows of 128B
    __shared__ __align__(16) __hip_bfloat16 Ps[8][16 * 64];  // 16 KB, per-wave P
    char* KsB = (char*)Ks;
    char* VTB = (char*)VTs;

    const int tid = threadIdx.x;
    const int bid = blockIdx.x;
    const int wgid = (bid & 7) * 32 + (bid >> 3);
    const int qb2 = wgid & 3, b = wgid >> 2;        // q-tile of 128 rows
    const int wid = tid >> 6, lane = tid & 63;
    const int l15 = lane & 15, lg = lane >> 4;
    char* PsB = (char*)(&Ps[wid][0]);

    short8 qf[8];
    const __hip_bfloat16* qrow = q + ((size_t)(b * 512 + qb2 * 128 + wid * 16 + l15)) * 256;
#pragma unroll
    for (int ks = 0; ks < 8; ++ks) qf[ks] = *(const short8*)(qrow + ks * 32 + lg * 8);

    float m_[4], lsum[4];
    floatx4 o[16];
#pragma unroll
    for (int r = 0; r < 4; ++r) { m_[r] = -1e30f; lsum[r] = 0.f; }
#pragma unroll
    for (int dt = 0; dt < 16; ++dt) o[dt] = (floatx4){0.f, 0.f, 0.f, 0.f};

    const int vkv = lane;
    const int vd0 = wid * 8;
    const int nchunks = qb2 * 2 + 2;
    const int qbw = qb2 * 128 + wid * 16;

    for (int c = 0; c < nchunks; ++c) {
        const size_t kvbase = (size_t)(b * 512 + c * 64) * 256;
#pragma unroll
        for (int s = 0; s < 4; ++s) {
            int o_ = s * 8192 + tid * 16;
            int row = o_ >> 9;
            int so = o_ ^ ((row & 7) << 4);
            const __hip_bfloat16* src = k + kvbase + (size_t)row * 256 + ((so & 511) >> 1);
            GLOAD_LDS16(src, KsB + o_);
        }
#pragma unroll
        for (int it = 0; it < 4; ++it) {
            int dbase = vd0 + it * 64;
            short8 vv = *(const short8*)(v + kvbase + (size_t)vkv * 256 + dbase);
#pragma unroll
            for (int j = 0; j < 8; ++j) {
                int d = dbase + j;
                int addr = (d * 128 + vkv * 2) ^ ((d & 7) << 4);
                *(short*)(VTB + addr) = vv[j];
            }
        }
        __syncthreads();

        floatx4 s4[4];
#pragma unroll
        for (int t = 0; t < 4; ++t) s4[t] = (floatx4){0.f, 0.f, 0.f, 0.f};
#pragma unroll
        for (int ks = 0; ks < 8; ++ks) {
#pragma unroll
            for (int t = 0; t < 4; ++t) {
                int kv = t * 16 + l15;
                short8 kf = *(const short8*)(KsB + kv * 512 + ((ks * 64 + lg * 16) ^ ((kv & 7) << 4)));
                s4[t] = mfma16(qf[ks], kf, s4[t]);
            }
        }
        if (c * 64 + 63 > qbw) {
#pragma unroll
            for (int t = 0; t < 4; ++t) {
                int kvg = c * 64 + t * 16 + l15;
#pragma unroll
                for (int r = 0; r < 4; ++r)
                    if (kvg > qbw + lg * 4 + r) s4[t][r] = -1e30f;
            }
        }
        float pm[4], alpha[4], rs[4];
#pragma unroll
        for (int r = 0; r < 4; ++r)
            pm[r] = fmaxf(fmaxf(s4[0][r], s4[1][r]), fmaxf(s4[2][r], s4[3][r]));
#pragma unroll
        for (int off = 1; off <= 8; off <<= 1)
#pragma unroll
            for (int r = 0; r < 4; ++r) pm[r] = fmaxf(pm[r], __shfl_xor(pm[r], off));
#pragma unroll
        for (int r = 0; r < 4; ++r) {
            float mn = fmaxf(m_[r], pm[r]);
            alpha[r] = exp2f(m_[r] - mn);
            m_[r] = mn;
        }
#pragma unroll
        for (int t = 0; t < 4; ++t)
#pragma unroll
            for (int r = 0; r < 4; ++r) s4[t][r] = exp2f(s4[t][r] - m_[r]);
#pragma unroll
        for (int r = 0; r < 4; ++r) rs[r] = s4[0][r] + s4[1][r] + s4[2][r] + s4[3][r];
#pragma unroll
        for (int off = 1; off <= 8; off <<= 1)
#pragma unroll
            for (int r = 0; r < 4; ++r) rs[r] += __shfl_xor(rs[r], off);
#pragma unroll
        for (int r = 0; r < 4; ++r) lsum[r] = lsum[r] * alpha[r] + rs[r];
#pragma unroll
        for (int dt = 0; dt < 16; ++dt) {
            o[dt][0] *= alpha[0]; o[dt][1] *= alpha[1];
            o[dt][2] *= alpha[2]; o[dt][3] *= alpha[3];
        }
#pragma unroll
        for (int t = 0; t < 4; ++t)
#pragma unroll
            for (int r = 0; r < 4; ++r) {
                int qq = lg * 4 + r;
                int addr = (qq * 128 + (t * 16 + l15) * 2) ^ ((qq & 7) << 4);
                *(short*)(PsB + addr) = f2bf(s4[t][r]);
            }
#pragma unroll
        for (int h = 0; h < 2; ++h) {
            short8 pa = *(const short8*)(PsB + l15 * 128 + ((h * 64 + lg * 16) ^ ((l15 & 7) << 4)));
#pragma unroll
            for (int dt = 0; dt < 16; ++dt) {
                int d = dt * 16 + l15;
                short8 vb = *(const short8*)(VTB + d * 128 + ((h * 64 + lg * 16) ^ ((d & 7) << 4)));
                o[dt] = mfma16(pa, vb, o[dt]);
            }
        }
        __syncthreads();
    }

    float inv[4];
#pragma unroll
    for (int r = 0; r < 4; ++r) inv[r] = 1.0f / lsum[r];
    size_t obase = ((size_t)(b * 512 + qb2 * 128 + wid * 16 + lg * 4)) * 256 + l15;
#pragma unroll
    for (int dt = 0; dt < 16; ++dt)
#pragma unroll
        for (int r = 0; r < 4; ++r)
            out[obase + (size_t)r * 256 + dt * 16] = o[dt][r] * inv[r];
}

// ---------------- host launch ----------------
extern "C" void kernel_launch(void* const* d_in, const int* in_sizes, int n_in,
                              void* d_out, int out_size, void* d_ws, size_t ws_size,
                              hipStream_t stream) {
    const float* x  = (const float*)d_in[0];
    const float* Wq = (const float*)d_in[1];
    const float* bq = (const float*)d_in[2];
    const float* Wk = (const float*)d_in[3];
    const float* bk = (const float*)d_in[4];
    const float* Wv = (const float*)d_in[5];
    const float* bv = (const float*)d_in[6];
    float* out = (float*)d_out;

    char* ws = (char*)d_ws;
    __hip_bfloat16* WT = (__hip_bfloat16*)ws;                       // 1.5 MiB @ 0
    __hip_bfloat16* qo = (__hip_bfloat16*)(ws + (2u << 20));        // 16 MiB each
    __hip_bfloat16* ko = qo + (size_t)32768 * 256;
    __hip_bfloat16* vo = ko + (size_t)32768 * 256;

    wconv_kernel<<<dim3(192), dim3(256), 0, stream>>>(Wq, Wk, Wv, WT);
    proj_kernel<<<dim3(256), dim3(512), 0, stream>>>(x, WT, bq, bk, bv, qo, ko, vo);
    attn_kernel<<<dim3(256), dim3(512), 0, stream>>>(qo, ko, vo, out);
}

// Round 23
// 128.786 us; speedup vs baseline: 1.5109x; 1.0038x over previous
//
#include <hip/hip_runtime.h>
#include <hip/hip_bf16.h>

typedef __attribute__((ext_vector_type(8))) short short8;
typedef __attribute__((ext_vector_type(4))) float floatx4;
typedef __attribute__((ext_vector_type(16))) float floatx16;

#define GLOAD_LDS16(src, dst) \
  __builtin_amdgcn_global_load_lds((const __attribute__((address_space(1))) unsigned int*)(src), \
      (__attribute__((address_space(3))) unsigned int*)(dst), 16, 0, 0)

__device__ __forceinline__ short f2bf(float f) {
    __hip_bfloat16 h = __float2bfloat16(f);
    return *reinterpret_cast<short*>(&h);
}

__device__ __forceinline__ floatx4 mfma16(short8 a, short8 b, floatx4 c) {
    return __builtin_amdgcn_mfma_f32_16x16x32_bf16(a, b, c, 0, 0, 0);
}

__device__ __forceinline__ floatx16 mfma32(short8 a, short8 b, floatx16 c) {
    return __builtin_amdgcn_mfma_f32_32x32x16_bf16(a, b, c, 0, 0, 0);
}

// ---------------- Kernel 1: W -> WTf (bf16, 32-col FRAGMENT-MAJOR, validated r20/21) --
// Fragment (kb, cb): cols cb*32..+32, k = kb*16..+16, 1 KB at (kb*24+cb)*1024.
// Lane l (= lh*32+l31) owns 16 B at l*16: 8 bf16 of column (cb*32+l31),
// k = kb*16+lh*8..+8 -- the exact 32x32x16 MFMA B operand. kb-major =>
// stage order == consumption order (enables within-kt phased waits).
__global__ __launch_bounds__(64) void wconv_kernel(const float* __restrict__ Wq,
                                                   const float* __restrict__ Wk,
                                                   const float* __restrict__ Wv,
                                                   __hip_bfloat16* __restrict__ WTf) {
    const int bid = blockIdx.x;          // 1536 = 64 kb x 24 cb
    const int kb = bid / 24;
    const int cb = bid % 24;
    const int lane = threadIdx.x;
    const int l31 = lane & 31, lh = lane >> 5;
    const int n = cb * 32 + l31;         // 0..767
    const float* W = (n < 256) ? Wq : (n < 512 ? Wk : Wv);
    const int nl = n & 255;
    const int k0 = kb * 16 + lh * 8;

    short8 h;
#pragma unroll
    for (int j = 0; j < 8; ++j)
        h[j] = f2bf(W[(size_t)(k0 + j) * 256 + nl]);
    *(short8*)((char*)WTf + (size_t)bid * 1024 + lane * 16) = h;
}

// ---------------- Kernel 2: projections  q,k,v = x @ W + b ----------------
// r14 geometry (BN=768, BM=128, BK=64, 256 blocks, 1/CU, 32x32x16 MFMA, x once)
// + fragment-major B + WITHIN-KT COUNTED-VMCNT PHASES (T3+T4):
//   issue A(4) + B chunks in consumption order (12); phase ks waits
//   vmcnt(9-3ks) + s_barrier and computes on chunk ks while B(ks+1..3) fly.
__global__ __launch_bounds__(512) void proj_kernel(const float* __restrict__ x,
                                                   const __hip_bfloat16* __restrict__ WTf,
                                                   const float* __restrict__ bq,
                                                   const float* __restrict__ bk,
                                                   const float* __restrict__ bv,
                                                   __hip_bfloat16* __restrict__ qo,
                                                   __hip_bfloat16* __restrict__ ko,
                                                   __hip_bfloat16* __restrict__ vo) {
    __shared__ __align__(16) char Ab[32768];   // 128 rows x 256B (64 fp32), swizzled
    __shared__ __align__(16) char Bb[98304];   // 96 fragments x 1KB, fragment-major
    const char* WfB = (const char*)WTf;

    const int tid = threadIdx.x;
    const int m0 = blockIdx.x * 128;        // 256 blocks; x panels exclusive
    const int wid = tid >> 6, lane = tid & 63;
    const int wm = wid >> 2, wn = wid & 3;  // wave tile: rows wm*64, cols wn*192
    const int l31 = lane & 31, lh = lane >> 5;

    floatx16 acc[2][6];
#pragma unroll
    for (int i = 0; i < 2; ++i)
#pragma unroll
        for (int j = 0; j < 6; ++j)
#pragma unroll
            for (int e = 0; e < 16; ++e) acc[i][j][e] = 0.f;

#define PHASE(KS, VMSTR) do {                                                        \
        __builtin_amdgcn_sched_barrier(0);                                           \
        asm volatile("s_waitcnt vmcnt(" VMSTR ")" ::: "memory");                     \
        __builtin_amdgcn_sched_barrier(0);                                           \
        __builtin_amdgcn_s_barrier();                                                \
        __builtin_amdgcn_sched_barrier(0);                                           \
        short8 af[2];                                                                \
        _Pragma("unroll")                                                            \
        for (int mt = 0; mt < 2; ++mt) {                                             \
            int row = wm * 64 + mt * 32 + l31;                                       \
            int rb = row * 256, msk = (row & 7) << 4;                                \
            int b0 = (KS) * 64 + lh * 32;                                            \
            floatx4 f0 = *(const floatx4*)(Ab + rb + (b0 ^ msk));                    \
            floatx4 f1 = *(const floatx4*)(Ab + rb + ((b0 + 16) ^ msk));             \
            short8 h;                                                                \
            h[0] = f2bf(f0[0]); h[1] = f2bf(f0[1]);                                  \
            h[2] = f2bf(f0[2]); h[3] = f2bf(f0[3]);                                  \
            h[4] = f2bf(f1[0]); h[5] = f2bf(f1[1]);                                  \
            h[6] = f2bf(f1[2]); h[7] = f2bf(f1[3]);                                  \
            af[mt] = h;                                                              \
        }                                                                            \
        __builtin_amdgcn_s_setprio(1);                                               \
        _Pragma("unroll")                                                            \
        for (int nt = 0; nt < 6; ++nt) {                                             \
            int f = (KS) * 24 + wn * 6 + nt;                                         \
            short8 b8 = *(const short8*)(Bb + (f << 10) + lane * 16);                \
            acc[0][nt] = mfma32(af[0], b8, acc[0][nt]);                              \
            acc[1][nt] = mfma32(af[1], b8, acc[1][nt]);                              \
        }                                                                            \
        __builtin_amdgcn_s_setprio(0);                                               \
    } while (0)

    for (int kt = 0; kt < 16; ++kt) {        // BK=64: k = kt*64..+64
        // ---- issue A stage (4 loads/thread, oldest)
#pragma unroll
        for (int s = 0; s < 4; ++s) {
            int o = s * 8192 + tid * 16;
            int row = o >> 8;
            int sb = (o & 255) ^ ((row & 7) << 4);    // inverse swizzle on source
            const float* src = x + (size_t)(m0 + row) * 1024 + kt * 64 + (sb >> 2);
            GLOAD_LDS16(src, Ab + o);
        }
        // ---- issue B stage in CONSUMPTION order: chunk ks = loads [3ks, 3ks+3)
#pragma unroll
        for (int s = 0; s < 12; ++s) {
            int o = s * 8192 + tid * 16;
            GLOAD_LDS16(WfB + (((size_t)kt * 96) << 10) + o, Bb + o);
        }
        // ---- 4 phases: compute chunk ks while chunks ks+1..3 are still in flight
        PHASE(0, "9");
        PHASE(1, "6");
        PHASE(2, "3");
        PHASE(3, "0");
        // ---- all waves done reading this kt's LDS before next stage overwrites
        __builtin_amdgcn_sched_barrier(0);
        __builtin_amdgcn_s_barrier();
        __builtin_amdgcn_sched_barrier(0);
    }
#undef PHASE

    // ---- epilogue: bias (+ log2e/16 scale for q), bf16 store
    // C/D layout (32x32): col = lane&31, row = (reg&3) + 8*(reg>>2) + 4*(lane>>5)
#pragma unroll
    for (int nt = 0; nt < 6; ++nt) {
        int g = wn * 192 + nt * 32 + l31;       // 0..767; mat uniform per (wave,nt)
        int mat = g >> 8;                       // 0=q 1=k 2=v
        const float* bias = (mat == 0) ? bq : (mat == 1 ? bk : bv);
        __hip_bfloat16* ob = (mat == 0) ? qo : (mat == 1 ? ko : vo);
        float scale = (mat == 0) ? 0.09016844005556021f : 1.0f;  // log2(e)/16
        int c = g & 255;
        float bval = bias[c];
#pragma unroll
        for (int mt = 0; mt < 2; ++mt) {
            int base_row = m0 + wm * 64 + mt * 32 + lh * 4;
#pragma unroll
            for (int reg = 0; reg < 16; ++reg) {
                int row = base_row + (reg & 3) + 8 * (reg >> 2);
                ob[(size_t)row * 256 + c] = __float2bfloat16((acc[mt][nt][reg] + bval) * scale);
            }
        }
    }
}

// ---------------- Kernel 3: causal flash attention (r18 version, best) ----------------
// QBLK=128 per block (8 waves x 16 q-rows), 256 blocks, LDS 80 KB -> 2 blocks/CU.
__global__ __launch_bounds__(512) void attn_kernel(const __hip_bfloat16* __restrict__ q,
                                                   const __hip_bfloat16* __restrict__ k,
                                                   const __hip_bfloat16* __restrict__ v,
                                                   float* __restrict__ out) {
    __shared__ __align__(16) __hip_bfloat16 Ks[64 * 256];    // 32 KB, swizzled rows of 512B
    __shared__ __align__(16) __hip_bfloat16 VTs[256 * 64];   // 32 KB, V^T, swizzled rows of 128B
    __shared__ __align__(16) __hip_bfloat16 Ps[8][16 * 64];  // 16 KB, per-wave P
    char* KsB = (char*)Ks;
    char* VTB = (char*)VTs;

    const int tid = threadIdx.x;
    const int bid = blockIdx.x;
    const int wgid = (bid & 7) * 32 + (bid >> 3);
    const int qb2 = wgid & 3, b = wgid >> 2;        // q-tile of 128 rows
    const int wid = tid >> 6, lane = tid & 63;
    const int l15 = lane & 15, lg = lane >> 4;
    char* PsB = (char*)(&Ps[wid][0]);

    short8 qf[8];
    const __hip_bfloat16* qrow = q + ((size_t)(b * 512 + qb2 * 128 + wid * 16 + l15)) * 256;
#pragma unroll
    for (int ks = 0; ks < 8; ++ks) qf[ks] = *(const short8*)(qrow + ks * 32 + lg * 8);

    float m_[4], lsum[4];
    floatx4 o[16];
#pragma unroll
    for (int r = 0; r < 4; ++r) { m_[r] = -1e30f; lsum[r] = 0.f; }
#pragma unroll
    for (int dt = 0; dt < 16; ++dt) o[dt] = (floatx4){0.f, 0.f, 0.f, 0.f};

    const int vkv = lane;
    const int vd0 = wid * 8;
    const int nchunks = qb2 * 2 + 2;
    const int qbw = qb2 * 128 + wid * 16;

    for (int c = 0; c < nchunks; ++c) {
        const size_t kvbase = (size_t)(b * 512 + c * 64) * 256;
#pragma unroll
        for (int s = 0; s < 4; ++s) {
            int o_ = s * 8192 + tid * 16;
            int row = o_ >> 9;
            int so = o_ ^ ((row & 7) << 4);
            const __hip_bfloat16* src = k + kvbase + (size_t)row * 256 + ((so & 511) >> 1);
            GLOAD_LDS16(src, KsB + o_);
        }
#pragma unroll
        for (int it = 0; it < 4; ++it) {
            int dbase = vd0 + it * 64;
            short8 vv = *(const short8*)(v + kvbase + (size_t)vkv * 256 + dbase);
#pragma unroll
            for (int j = 0; j < 8; ++j) {
                int d = dbase + j;
                int addr = (d * 128 + vkv * 2) ^ ((d & 7) << 4);
                *(short*)(VTB + addr) = vv[j];
            }
        }
        __syncthreads();

        floatx4 s4[4];
#pragma unroll
        for (int t = 0; t < 4; ++t) s4[t] = (floatx4){0.f, 0.f, 0.f, 0.f};
#pragma unroll
        for (int ks = 0; ks < 8; ++ks) {
#pragma unroll
            for (int t = 0; t < 4; ++t) {
                int kv = t * 16 + l15;
                short8 kf = *(const short8*)(KsB + kv * 512 + ((ks * 64 + lg * 16) ^ ((kv & 7) << 4)));
                s4[t] = mfma16(qf[ks], kf, s4[t]);
            }
        }
        if (c * 64 + 63 > qbw) {
#pragma unroll
            for (int t = 0; t < 4; ++t) {
                int kvg = c * 64 + t * 16 + l15;
#pragma unroll
                for (int r = 0; r < 4; ++r)
                    if (kvg > qbw + lg * 4 + r) s4[t][r] = -1e30f;
            }
        }
        float pm[4], alpha[4], rs[4];
#pragma unroll
        for (int r = 0; r < 4; ++r)
            pm[r] = fmaxf(fmaxf(s4[0][r], s4[1][r]), fmaxf(s4[2][r], s4[3][r]));
#pragma unroll
        for (int off = 1; off <= 8; off <<= 1)
#pragma unroll
            for (int r = 0; r < 4; ++r) pm[r] = fmaxf(pm[r], __shfl_xor(pm[r], off));
#pragma unroll
        for (int r = 0; r < 4; ++r) {
            float mn = fmaxf(m_[r], pm[r]);
            alpha[r] = exp2f(m_[r] - mn);
            m_[r] = mn;
        }
#pragma unroll
        for (int t = 0; t < 4; ++t)
#pragma unroll
            for (int r = 0; r < 4; ++r) s4[t][r] = exp2f(s4[t][r] - m_[r]);
#pragma unroll
        for (int r = 0; r < 4; ++r) rs[r] = s4[0][r] + s4[1][r] + s4[2][r] + s4[3][r];
#pragma unroll
        for (int off = 1; off <= 8; off <<= 1)
#pragma unroll
            for (int r = 0; r < 4; ++r) rs[r] += __shfl_xor(rs[r], off);
#pragma unroll
        for (int r = 0; r < 4; ++r) lsum[r] = lsum[r] * alpha[r] + rs[r];
#pragma unroll
        for (int dt = 0; dt < 16; ++dt) {
            o[dt][0] *= alpha[0]; o[dt][1] *= alpha[1];
            o[dt][2] *= alpha[2]; o[dt][3] *= alpha[3];
        }
#pragma unroll
        for (int t = 0; t < 4; ++t)
#pragma unroll
            for (int r = 0; r < 4; ++r) {
                int qq = lg * 4 + r;
                int addr = (qq * 128 + (t * 16 + l15) * 2) ^ ((qq & 7) << 4);
                *(short*)(PsB + addr) = f2bf(s4[t][r]);
            }
#pragma unroll
        for (int h = 0; h < 2; ++h) {
            short8 pa = *(const short8*)(PsB + l15 * 128 + ((h * 64 + lg * 16) ^ ((l15 & 7) << 4)));
#pragma unroll
            for (int dt = 0; dt < 16; ++dt) {
                int d = dt * 16 + l15;
                short8 vb = *(const short8*)(VTB + d * 128 + ((h * 64 + lg * 16) ^ ((d & 7) << 4)));
                o[dt] = mfma16(pa, vb, o[dt]);
            }
        }
        __syncthreads();
    }

    float inv[4];
#pragma unroll
    for (int r = 0; r < 4; ++r) inv[r] = 1.0f / lsum[r];
    size_t obase = ((size_t)(b * 512 + qb2 * 128 + wid * 16 + lg * 4)) * 256 + l15;
#pragma unroll
    for (int dt = 0; dt < 16; ++dt)
#pragma unroll
        for (int r = 0; r < 4; ++r)
            out[obase + (size_t)r * 256 + dt * 16] = o[dt][r] * inv[r];
}

// ---------------- host launch ----------------
extern "C" void kernel_launch(void* const* d_in, const int* in_sizes, int n_in,
                              void* d_out, int out_size, void* d_ws, size_t ws_size,
                              hipStream_t stream) {
    const float* x  = (const float*)d_in[0];
    const float* Wq = (const float*)d_in[1];
    const float* bq = (const float*)d_in[2];
    const float* Wk = (const float*)d_in[3];
    const float* bk = (const float*)d_in[4];
    const float* Wv = (const float*)d_in[5];
    const float* bv = (const float*)d_in[6];
    float* out = (float*)d_out;

    char* ws = (char*)d_ws;
    __hip_bfloat16* WTf = (__hip_bfloat16*)ws;                      // 1.5 MiB @ 0
    __hip_bfloat16* qo = (__hip_bfloat16*)(ws + (2u << 20));        // 16 MiB each
    __hip_bfloat16* ko = qo + (size_t)32768 * 256;
    __hip_bfloat16* vo = ko + (size_t)32768 * 256;

    wconv_kernel<<<dim3(1536), dim3(64), 0, stream>>>(Wq, Wk, Wv, WTf);
    proj_kernel<<<dim3(256), dim3(512), 0, stream>>>(x, WTf, bq, bk, bv, qo, ko, vo);
    attn_kernel<<<dim3(256), dim3(512), 0, stream>>>(qo, ko, vo, out);
}